// Round 8
// baseline (2230.115 us; speedup 1.0000x reference)
//
#include <hip/hip_runtime.h>

#define DEV __device__ __forceinline__

constexpr int Nn  = 50000;
constexpr int Ee  = 800000;
constexpr int Et  = 850000;   // E + N self loops
constexpr int Gg  = 16;
constexpr int Dd  = 64;
constexpr int Hh  = 4;
constexpr int Ll  = 4;
constexpr int INd = 7;
constexpr float NEG  = 0.2f;
constexpr float EPSL = 1e-5f;

DEV float lrelu(float x){ return fmaxf(x, NEG*x); }
DEV float wsum64(float v){
  v += __shfl_xor(v,1); v += __shfl_xor(v,2); v += __shfl_xor(v,4);
  v += __shfl_xor(v,8); v += __shfl_xor(v,16); v += __shfl_xor(v,32);
  return v;
}
DEV void atomicMaxF(float* a, float v){
  if (v >= 0.f) atomicMax((int*)a, __float_as_int(v));
  else          atomicMin((unsigned int*)a, __float_as_uint(v));
}

// ---------------- setup kernels ----------------

__global__ void k_init(int* deg, float* g_sum, float* g_max, int* grp_cnt, float* ea_sum){
  int i = blockIdx.x*256 + threadIdx.x;
  if (i < Nn) deg[i] = 0;
  if (i < Gg*Dd){ g_sum[i] = 0.f; g_max[i] = -3.4e38f; }
  if (i < Gg) grp_cnt[i] = 0;
  if (i < 3) ea_sum[i] = 0.f;
}

__global__ void k_eamean(const float* __restrict__ ea, float* __restrict__ ea_sum){
  __shared__ float ps[4][3];
  int tid = threadIdx.x;
  float s0=0.f, s1=0.f, s2=0.f;
  int stride = gridDim.x * blockDim.x;
  for (int i = blockIdx.x*blockDim.x + tid; i < Ee; i += stride){
    s0 += ea[3*i]; s1 += ea[3*i+1]; s2 += ea[3*i+2];
  }
  s0 = wsum64(s0); s1 = wsum64(s1); s2 = wsum64(s2);
  int wid = tid >> 6;
  if ((tid & 63) == 0){ ps[wid][0]=s0; ps[wid][1]=s1; ps[wid][2]=s2; }
  __syncthreads();
  if (tid == 0){
    atomicAdd(ea_sum+0, ps[0][0]+ps[1][0]+ps[2][0]+ps[3][0]);
    atomicAdd(ea_sum+1, ps[0][1]+ps[1][1]+ps[2][1]+ps[3][1]);
    atomicAdd(ea_sum+2, ps[0][2]+ps[1][2]+ps[2][2]+ps[3][2]);
  }
}

__global__ void k_deg(const int* __restrict__ ei_dst, int* __restrict__ deg){
  int e = blockIdx.x*256 + threadIdx.x;
  if (e >= Et) return;
  int dst = (e < Ee) ? ei_dst[e] : (e - Ee);
  atomicAdd(&deg[dst], 1);
}

__global__ void k_bcnt(const int* __restrict__ batch, int* __restrict__ grp_cnt){
  __shared__ int c[Gg];
  if (threadIdx.x < Gg) c[threadIdx.x] = 0;
  __syncthreads();
  int i = blockIdx.x*256 + threadIdx.x;
  if (i < Nn) atomicAdd(&c[batch[i]], 1);
  __syncthreads();
  if (threadIdx.x < Gg && c[threadIdx.x]) atomicAdd(&grp_cnt[threadIdx.x], c[threadIdx.x]);
}

__global__ __launch_bounds__(1024) void k_scan(
    const int* __restrict__ deg, int* __restrict__ indptr, int* __restrict__ fill,
    const float* __restrict__ ea_sum, float* __restrict__ ea_mean)
{
  __shared__ int tot[1024];
  int tid = threadIdx.x;
  if (tid < 3) ea_mean[tid] = ea_sum[tid] * (1.f/(float)Ee);
  constexpr int CH = (Nn + 1023)/1024;   // 49
  int b0 = tid*CH;
  int loc[CH];
  int s = 0;
  #pragma unroll
  for (int i=0;i<CH;++i){
    int idx = b0+i;
    int d = (idx < Nn) ? deg[idx] : 0;
    loc[i] = s; s += d;
  }
  tot[tid] = s;
  __syncthreads();
  for (int off=1; off<1024; off<<=1){
    int v = (tid>=off) ? tot[tid-off] : 0;
    __syncthreads();
    tot[tid] += v;
    __syncthreads();
  }
  int base = (tid==0) ? 0 : tot[tid-1];
  #pragma unroll
  for (int i=0;i<CH;++i){
    int idx = b0+i;
    if (idx < Nn){
      int ex = base + loc[i];
      fill[idx] = ex;
      indptr[idx+1] = ex + deg[idx];
    }
  }
  if (tid==0) indptr[0] = 0;
}

// scatter edge meta {src, a0, a1, a2} into CSR slots (self-loop attrs = ea_mean)
__global__ void k_scatter(const int* __restrict__ ei_src, const int* __restrict__ ei_dst,
                          const float* __restrict__ ea, const float* __restrict__ ea_mean,
                          int* __restrict__ fill, float4* __restrict__ meta){
  int e = blockIdx.x*256 + threadIdx.x;
  if (e >= Et) return;
  int src, dst; float a0, a1, a2;
  if (e < Ee){
    src = ei_src[e]; dst = ei_dst[e];
    a0 = ea[3*e]; a1 = ea[3*e+1]; a2 = ea[3*e+2];
  } else {
    src = dst = e - Ee;
    a0 = ea_mean[0]; a1 = ea_mean[1]; a2 = ea_mean[2];
  }
  int pos = atomicAdd(&fill[dst], 1);
  meta[pos] = make_float4(__int_as_float(src), a0, a1, a2);
}

// transpose fW1 (L x 64 x 128 -> L x 128 x 64) and gW1 (L x 64 x 64 -> T)
__global__ void k_tw(const float* __restrict__ fW1, const float* __restrict__ gW1,
                     float* __restrict__ fW1T, float* __restrict__ gW1T){
  int i = blockIdx.x*256 + threadIdx.x;
  if (i < Ll*64*128){
    int l = i >> 13, r = (i >> 7) & 63, c = i & 127;
    fW1T[l*8192 + c*64 + r] = fW1[i];
  }
  if (i < Ll*64*64){
    int l = i >> 12, r = (i >> 6) & 63, c = i & 63;
    gW1T[l*4096 + c*64 + r] = gW1[i];
  }
}

// ---------------- encoder ----------------

__global__ __launch_bounds__(256) void k_enc(
    const float* __restrict__ x, const float* __restrict__ W, const float* __restrict__ b,
    float* __restrict__ h)
{
  int i = blockIdx.x*256 + threadIdx.x;
  if (i >= Nn*Dd) return;
  int n = i >> 6, d = i & 63;
  float s = b[d];
  #pragma unroll
  for (int k=0;k<INd;++k) s = fmaf(x[n*INd+k], W[k*Dd+d], s);
  h[i] = s;
}

// ---------------- xl/xr GEMM (+ gate apply from previous layer) ----------------

__global__ __launch_bounds__(256) void k_xlxr(
    float* __restrict__ h, const float* __restrict__ gate, const int* __restrict__ batch,
    const float* __restrict__ Wl, const float* __restrict__ bl,
    const float* __restrict__ Wr, const float* __restrict__ br,
    float* __restrict__ xl, float* __restrict__ xr)
{
  __shared__ float lh[32*68];
  int tid = threadIdx.x;
  int n0 = blockIdx.x * 32;
  for (int r=0; r<8; ++r){
    int idx = r*256 + tid;
    int nl = idx >> 6, d = idx & 63;
    int node = n0 + nl;
    float v = 0.f;
    if (node < Nn){
      v = h[(size_t)node*64 + d];
      if (gate){ v *= gate[batch[node]*64 + d]; h[(size_t)node*64 + d] = v; }
    }
    lh[nl*68 + d] = v;
  }
  __syncthreads();
  int lane = tid & 63;
  int nb = (tid >> 6) * 8;
  int c0 = lane * 8;
  const float* W; const float* bb; float* outp; int col;
  if (c0 < 256){ W = Wl; bb = bl; outp = xl; col = c0; }
  else         { W = Wr; bb = br; outp = xr; col = c0 - 256; }
  float4 bA = *reinterpret_cast<const float4*>(bb + col);
  float4 bB = *reinterpret_cast<const float4*>(bb + col + 4);
  float acc[8][8];
  #pragma unroll
  for (int nq=0; nq<8; ++nq){
    acc[nq][0]=bA.x; acc[nq][1]=bA.y; acc[nq][2]=bA.z; acc[nq][3]=bA.w;
    acc[nq][4]=bB.x; acc[nq][5]=bB.y; acc[nq][6]=bB.z; acc[nq][7]=bB.w;
  }
  for (int d=0; d<64; d+=4){
    float4 wA[4], wB[4];
    #pragma unroll
    for (int dq=0; dq<4; ++dq){
      wA[dq] = *reinterpret_cast<const float4*>(W + (d+dq)*256 + col);
      wB[dq] = *reinterpret_cast<const float4*>(W + (d+dq)*256 + col + 4);
    }
    #pragma unroll
    for (int nq=0; nq<8; ++nq){
      float4 hv = *reinterpret_cast<const float4*>(&lh[(nb+nq)*68 + d]);
      #pragma unroll
      for (int dq=0; dq<4; ++dq){
        float hh = (dq==0)? hv.x : (dq==1)? hv.y : (dq==2)? hv.z : hv.w;
        acc[nq][0] = fmaf(hh, wA[dq].x, acc[nq][0]);
        acc[nq][1] = fmaf(hh, wA[dq].y, acc[nq][1]);
        acc[nq][2] = fmaf(hh, wA[dq].z, acc[nq][2]);
        acc[nq][3] = fmaf(hh, wA[dq].w, acc[nq][3]);
        acc[nq][4] = fmaf(hh, wB[dq].x, acc[nq][4]);
        acc[nq][5] = fmaf(hh, wB[dq].y, acc[nq][5]);
        acc[nq][6] = fmaf(hh, wB[dq].z, acc[nq][6]);
        acc[nq][7] = fmaf(hh, wB[dq].w, acc[nq][7]);
      }
    }
  }
  #pragma unroll
  for (int nq=0; nq<8; ++nq){
    int node = n0 + nb + nq;
    if (node < Nn){
      float4 oA = make_float4(acc[nq][0],acc[nq][1],acc[nq][2],acc[nq][3]);
      float4 oB = make_float4(acc[nq][4],acc[nq][5],acc[nq][6],acc[nq][7]);
      *reinterpret_cast<float4*>(outp + (size_t)node*256 + col)     = oA;
      *reinterpret_cast<float4*>(outp + (size_t)node*256 + col + 4) = oB;
    }
  }
}

// ---------------- edge phase: GATv2 attention aggregation ----------------

__global__ __launch_bounds__(256) void k_edge(
    const float* __restrict__ xl, const float* __restrict__ xr,
    const int* __restrict__ indptr, const float4* __restrict__ meta,
    const float* __restrict__ We, const float* __restrict__ att,
    float* __restrict__ gat_out)
{
  int lane = threadIdx.x & 63;
  int n = __builtin_amdgcn_readfirstlane(blockIdx.x*4 + (threadIdx.x>>6));
  int coff = (lane>>4)*64 + (lane & 15)*4;

  const float4 xr4 = *reinterpret_cast<const float4*>(xr + (size_t)n*256 + coff);
  const float4 we0 = *reinterpret_cast<const float4*>(We + 0*256 + coff);
  const float4 we1 = *reinterpret_cast<const float4*>(We + 1*256 + coff);
  const float4 we2 = *reinterpret_cast<const float4*>(We + 2*256 + coff);
  const float4 aw  = *reinterpret_cast<const float4*>(att + coff);

  int p0 = __builtin_amdgcn_readfirstlane(indptr[n]);
  int p1 = __builtin_amdgcn_readfirstlane(indptr[n+1]);
  int cnt = p1 - p0;                       // >= 1 (self loop)
  const float4* __restrict__ mp = meta + p0;
  int lane7 = lane & 7;
  int ntiles = (cnt + 7) >> 3;

  float den = 0.f, a0c=0.f, a1c=0.f, a2c=0.f, a3c=0.f;

  auto ldm = [&](int t) -> float4 {
    int idx = t*8 + lane7;
    idx = idx < cnt-1 ? idx : cnt-1;
    return mp[idx];
  };
  auto issueXv = [&](const float4& mb, float4 (&xv)[8]){
    #pragma unroll
    for (int i=0;i<8;++i){
      int s = __float_as_int(__shfl(mb.x, i));
      xv[i] = *reinterpret_cast<const float4*>(xl + (size_t)s*256 + coff);
    }
  };
  auto compute = [&](const float4& mb, const float4 (&xv)[8], int t){
    #pragma unroll
    for (int i=0;i<8;++i){
      float a0 = __shfl(mb.y, i), a1 = __shfl(mb.z, i), a2 = __shfl(mb.w, i);
      float t0 = fmaf(a0, we0.x, xr4.x); t0 = fmaf(a1, we1.x, t0); t0 = fmaf(a2, we2.x, t0);
      float t1 = fmaf(a0, we0.y, xr4.y); t1 = fmaf(a1, we1.y, t1); t1 = fmaf(a2, we2.y, t1);
      float t2 = fmaf(a0, we0.z, xr4.z); t2 = fmaf(a1, we1.z, t2); t2 = fmaf(a2, we2.z, t2);
      float t3 = fmaf(a0, we0.w, xr4.w); t3 = fmaf(a1, we1.w, t3); t3 = fmaf(a2, we2.w, t3);
      float u0 = lrelu(xv[i].x + t0), u1 = lrelu(xv[i].y + t1);
      float u2 = lrelu(xv[i].z + t2), u3 = lrelu(xv[i].w + t3);
      float part = fmaf(u0, aw.x, fmaf(u1, aw.y, fmaf(u2, aw.z, u3*aw.w)));
      part += __shfl_xor(part,1); part += __shfl_xor(part,2);
      part += __shfl_xor(part,4); part += __shfl_xor(part,8);
      float w = (t*8 + i < cnt) ? __expf(part) : 0.f;   // logits tiny: no max needed
      den += w;
      a0c = fmaf(w, xv[i].x, a0c);
      a1c = fmaf(w, xv[i].y, a1c);
      a2c = fmaf(w, xv[i].z, a2c);
      a3c = fmaf(w, xv[i].w, a3c);
    }
  };

  float4 xvA[8], xvB[8];
  float4 mCur = ldm(0);
  float4 mNxt = (ntiles > 1) ? ldm(1) : mCur;
  float4 mN2  = mCur;
  issueXv(mCur, xvA);

  int t = 0;
  while (true){
    if (t+2 < ntiles) mN2 = ldm(t+2);
    if (t+1 < ntiles) issueXv(mNxt, xvB);
    compute(mCur, xvA, t);
    if (t+1 >= ntiles) break;
    if (t+3 < ntiles) mCur = ldm(t+3);
    if (t+2 < ntiles) issueXv(mN2, xvA);
    compute(mNxt, xvB, t+1);
    if (t+2 >= ntiles) break;
    float4 tm = mCur; mCur = mN2; mNxt = tm;
    t += 2;
  }

  float inv = 1.f/(den*(float)Hh);
  float s0=a0c*inv, s1=a1c*inv, s2=a2c*inv, s3=a3c*inv;
  s0 += __shfl_xor(s0,16); s0 += __shfl_xor(s0,32);
  s1 += __shfl_xor(s1,16); s1 += __shfl_xor(s1,32);
  s2 += __shfl_xor(s2,16); s2 += __shfl_xor(s2,32);
  s3 += __shfl_xor(s3,16); s3 += __shfl_xor(s3,32);
  int srcl = lane >> 2;
  float w0 = __shfl(s0, srcl), w1 = __shfl(s1, srcl);
  float w2 = __shfl(s2, srcl), w3 = __shfl(s3, srcl);
  int kk = lane & 3;
  float gat = (kk==0)? w0 : (kk==1)? w1 : (kk==2)? w2 : w3;
  gat_out[(size_t)n*64 + lane] = gat;
}

// ---------------- node phase v4: lane = node, 4-wave cooperative c-split ----------------
// Block = 256 (4 waves) covering the SAME 64 nodes (node = blockIdx*64 + lane).
// Wave wv computes hidden cols [wv*32,wv*32+32) of FFN (and [wv*16,+16) of latent);
// partial o[64] combined via padded LDS (stride 69 -> <=2-way conflicts). Weight
// indices remain wave-uniform -> scalar s_load. LN1/LN2 recomputed redundantly
// per wave (register-only). 4x waves vs v3 -> latency hiding.

__global__ __launch_bounds__(256) void k_node(
    float* __restrict__ h, const float* __restrict__ gat,
    const float* __restrict__ gatb,
    const float* __restrict__ ln1w, const float* __restrict__ ln1b,
    const float* __restrict__ fW1T, const float* __restrict__ fb1,
    const float* __restrict__ fW2,  const float* __restrict__ fb2,
    const float* __restrict__ ln2w, const float* __restrict__ ln2b,
    const float* __restrict__ gW1T, const float* __restrict__ gb1,
    const float* __restrict__ gW2,  const float* __restrict__ gb2,
    const int* __restrict__ batch, float* __restrict__ g_sum, float* __restrict__ g_max)
{
  __shared__ float sO[4][64][69];
  __shared__ int   sB[64];
  int lane = threadIdx.x & 63;
  int wv   = threadIdx.x >> 6;
  int n = blockIdx.x*64 + lane;
  bool valid = n < Nn;
  if (wv == 0) sB[lane] = valid ? batch[n] : -1;

  // ---- load x = h[n] + gat[n] + gatb (all waves, redundant) ----
  float x[64];
  if (valid){
    #pragma unroll
    for (int q=0; q<16; ++q){
      float4 a = *reinterpret_cast<const float4*>(h   + (size_t)n*64 + q*4);
      float4 b = *reinterpret_cast<const float4*>(gat + (size_t)n*64 + q*4);
      float4 g = *reinterpret_cast<const float4*>(gatb + q*4);
      x[q*4+0] = a.x + b.x + g.x;
      x[q*4+1] = a.y + b.y + g.y;
      x[q*4+2] = a.z + b.z + g.z;
      x[q*4+3] = a.w + b.w + g.w;
    }
  } else {
    #pragma unroll
    for (int d=0; d<64; ++d) x[d] = 0.f;
  }

  // ---- LN1 (in-lane) ----
  {
    float s0=0,s1=0,s2=0,s3=0;
    #pragma unroll
    for (int d=0; d<64; d+=4){ s0+=x[d]; s1+=x[d+1]; s2+=x[d+2]; s3+=x[d+3]; }
    float mean = ((s0+s1)+(s2+s3)) * (1.f/64.f);
    float v0=0,v1=0,v2=0,v3=0;
    #pragma unroll
    for (int d=0; d<64; d+=4){
      float a=x[d]-mean, b=x[d+1]-mean, c=x[d+2]-mean, e=x[d+3]-mean;
      v0=fmaf(a,a,v0); v1=fmaf(b,b,v1); v2=fmaf(c,c,v2); v3=fmaf(e,e,v3);
    }
    float rstd = rsqrtf(((v0+v1)+(v2+v3))*(1.f/64.f) + EPSL);
    #pragma unroll
    for (int d=0; d<64; ++d) x[d] = (x[d]-mean)*rstd*ln1w[d] + ln1b[d];
  }

  // ---- FFN partial: this wave's 32 hidden cols ----
  float o[64];
  if (wv == 0){
    #pragma unroll
    for (int j=0; j<64; ++j) o[j] = fb2[j];
  } else {
    #pragma unroll
    for (int j=0; j<64; ++j) o[j] = 0.f;
  }
  {
    int c0 = wv*32;
    #pragma unroll 2
    for (int c=c0; c<c0+32; ++c){
      const float* __restrict__ w1 = fW1T + c*64;
      float a0=0,a1=0,a2=0,a3=0;
      #pragma unroll
      for (int d=0; d<64; d+=4){
        a0 = fmaf(x[d],   w1[d],   a0);
        a1 = fmaf(x[d+1], w1[d+1], a1);
        a2 = fmaf(x[d+2], w1[d+2], a2);
        a3 = fmaf(x[d+3], w1[d+3], a3);
      }
      float hc = lrelu((a0+a1)+(a2+a3) + fb1[c]);
      const float* __restrict__ w2 = fW2 + c*64;
      #pragma unroll
      for (int j=0; j<64; ++j) o[j] = fmaf(hc, w2[j], o[j]);
    }
  }
  #pragma unroll
  for (int j=0; j<64; j+=4)
    *reinterpret_cast<float4*>(&sO[wv][lane][j]) = make_float4(o[j],o[j+1],o[j+2],o[j+3]);
  __syncthreads();
  // sum partials (all waves, redundant)
  #pragma unroll
  for (int j=0; j<64; j+=4){
    float4 p0 = *reinterpret_cast<const float4*>(&sO[0][lane][j]);
    float4 p1 = *reinterpret_cast<const float4*>(&sO[1][lane][j]);
    float4 p2 = *reinterpret_cast<const float4*>(&sO[2][lane][j]);
    float4 p3 = *reinterpret_cast<const float4*>(&sO[3][lane][j]);
    o[j]   = (p0.x+p1.x)+(p2.x+p3.x);
    o[j+1] = (p0.y+p1.y)+(p2.y+p3.y);
    o[j+2] = (p0.z+p1.z)+(p2.z+p3.z);
    o[j+3] = (p0.w+p1.w)+(p2.w+p3.w);
  }
  __syncthreads();   // all reads of FFN partials done before latent writes reuse sO

  // ---- residual + LN2 -> hn (in x); wave 0 stores h ----
  {
    #pragma unroll
    for (int d=0; d<64; ++d) x[d] += o[d];
    float s0=0,s1=0,s2=0,s3=0;
    #pragma unroll
    for (int d=0; d<64; d+=4){ s0+=x[d]; s1+=x[d+1]; s2+=x[d+2]; s3+=x[d+3]; }
    float mean = ((s0+s1)+(s2+s3)) * (1.f/64.f);
    float v0=0,v1=0,v2=0,v3=0;
    #pragma unroll
    for (int d=0; d<64; d+=4){
      float a=x[d]-mean, b=x[d+1]-mean, c=x[d+2]-mean, e=x[d+3]-mean;
      v0=fmaf(a,a,v0); v1=fmaf(b,b,v1); v2=fmaf(c,c,v2); v3=fmaf(e,e,v3);
    }
    float rstd = rsqrtf(((v0+v1)+(v2+v3))*(1.f/64.f) + EPSL);
    #pragma unroll
    for (int d=0; d<64; ++d) x[d] = (x[d]-mean)*rstd*ln2w[d] + ln2b[d];
    if (valid && wv == 0){
      #pragma unroll
      for (int q=0; q<16; ++q){
        *reinterpret_cast<float4*>(h + (size_t)n*64 + q*4) =
            make_float4(x[q*4], x[q*4+1], x[q*4+2], x[q*4+3]);
      }
    }
  }

  // ---- latent partial: this wave's 16 cols ----
  if (wv == 0){
    #pragma unroll
    for (int j=0; j<64; ++j) o[j] = gb2[j];
  } else {
    #pragma unroll
    for (int j=0; j<64; ++j) o[j] = 0.f;
  }
  {
    int c0 = wv*16;
    #pragma unroll 2
    for (int c=c0; c<c0+16; ++c){
      const float* __restrict__ w1 = gW1T + c*64;
      float a0=0,a1=0,a2=0,a3=0;
      #pragma unroll
      for (int d=0; d<64; d+=4){
        a0 = fmaf(x[d],   w1[d],   a0);
        a1 = fmaf(x[d+1], w1[d+1], a1);
        a2 = fmaf(x[d+2], w1[d+2], a2);
        a3 = fmaf(x[d+3], w1[d+3], a3);
      }
      float uc = lrelu((a0+a1)+(a2+a3) + gb1[c]);
      const float* __restrict__ w2 = gW2 + c*64;
      #pragma unroll
      for (int j=0; j<64; ++j) o[j] = fmaf(uc, w2[j], o[j]);
    }
  }
  #pragma unroll
  for (int j=0; j<64; j+=4)
    *reinterpret_cast<float4*>(&sO[wv][lane][j]) = make_float4(o[j],o[j+1],o[j+2],o[j+3]);
  __syncthreads();
  if (wv != 0) return;

  // ---- wave 0: sum latent partials, transpose, sorted-run group atomics ----
  float lat[64];
  #pragma unroll
  for (int j=0; j<64; j+=4){
    float4 p0 = *reinterpret_cast<const float4*>(&sO[0][lane][j]);
    float4 p1 = *reinterpret_cast<const float4*>(&sO[1][lane][j]);
    float4 p2 = *reinterpret_cast<const float4*>(&sO[2][lane][j]);
    float4 p3 = *reinterpret_cast<const float4*>(&sO[3][lane][j]);
    lat[j]   = (p0.x+p1.x)+(p2.x+p3.x);
    lat[j+1] = (p0.y+p1.y)+(p2.y+p3.y);
    lat[j+2] = (p0.z+p1.z)+(p2.z+p3.z);
    lat[j+3] = (p0.w+p1.w)+(p2.w+p3.w);
  }
  float* sL = &sO[0][0][0];   // [64][67] alias; wave-0-private now
  #pragma unroll
  for (int j=0; j<64; ++j) sL[j*67 + lane] = lat[j];
  {
    int cur = -1; float acc = 0.f, mx = -3.4e38f;
    for (int nn=0; nn<64; ++nn){
      int gv = sB[nn];
      float v = sL[lane*67 + nn];
      if (gv != cur){
        if (cur >= 0){
          atomicAdd(g_sum + cur*64 + lane, acc);
          atomicMaxF(g_max + cur*64 + lane, mx);
        }
        cur = gv; acc = 0.f; mx = -3.4e38f;
      }
      if (gv >= 0){ acc += v; mx = fmaxf(mx, v); }
    }
    if (cur >= 0){
      atomicAdd(g_sum + cur*64 + lane, acc);
      atomicMaxF(g_max + cur*64 + lane, mx);
    }
  }
}

// ---------------- gate (one block), also resets accumulators ----------------

__global__ __launch_bounds__(1024) void k_gate(
    float* __restrict__ g_sum, float* __restrict__ g_max, const int* __restrict__ grp_cnt,
    const float* __restrict__ gW, const float* __restrict__ gb, float* __restrict__ gate)
{
  __shared__ float sme[Gg*64];
  __shared__ float smx[Gg*64];
  int tid = threadIdx.x;
  int g = tid >> 6, d = tid & 63;
  float cnt = fmaxf((float)grp_cnt[g], 1.f);
  sme[tid] = g_sum[tid] / cnt;
  smx[tid] = g_max[tid];
  __syncthreads();
  float a = gb[d];
  #pragma unroll
  for (int j=0;j<64;++j){
    a = fmaf(sme[g*64+j], gW[j*64+d],      a);
    a = fmaf(smx[g*64+j], gW[(64+j)*64+d], a);
  }
  gate[tid] = 1.f/(1.f + __expf(-a));
  g_sum[tid] = 0.f;
  g_max[tid] = -3.4e38f;
}

// ---------------- decoder (applies final gate) ----------------

__global__ __launch_bounds__(256) void k_dec(
    const float* __restrict__ h, const float* __restrict__ gate, const int* __restrict__ batch,
    const float* __restrict__ W1, const float* __restrict__ b1,
    const float* __restrict__ W2, const float* __restrict__ b2,
    float* __restrict__ out)
{
  int lane = threadIdx.x & 63;
  int n = __builtin_amdgcn_readfirstlane(blockIdx.x*4 + (threadIdx.x>>6));
  float hv = h[(size_t)n*64 + lane] * gate[batch[n]*64 + lane];
  float hid = b1[lane];
  #pragma unroll
  for (int d2=0; d2<64; ++d2) hid = fmaf(__shfl(hv,d2), W1[d2*64+lane], hid);
  hid = lrelu(hid);
  float r0 = wsum64(hid * W2[lane*2+0]);
  float r1 = wsum64(hid * W2[lane*2+1]);
  if (lane == 0){
    out[(size_t)n*2]   = r0 + b2[0];
    out[(size_t)n*2+1] = r1 + b2[1];
  }
}

// ---------------- launch ----------------

extern "C" void kernel_launch(void* const* d_in, const int* in_sizes, int n_in,
                              void* d_out, int out_size, void* d_ws, size_t ws_size,
                              hipStream_t stream) {
  const float* x    = (const float*)d_in[0];
  const float* ea   = (const float*)d_in[1];
  const int*   ei   = (const int*)  d_in[2];
  const int*   bat  = (const int*)  d_in[3];
  const float* encW = (const float*)d_in[4];
  const float* encb = (const float*)d_in[5];
  const float* Wl   = (const float*)d_in[6];
  const float* bl   = (const float*)d_in[7];
  const float* Wr   = (const float*)d_in[8];
  const float* br   = (const float*)d_in[9];
  const float* We   = (const float*)d_in[10];
  const float* attw = (const float*)d_in[11];
  const float* gatb = (const float*)d_in[12];
  const float* ln1w = (const float*)d_in[13];
  const float* ln1b = (const float*)d_in[14];
  const float* ln2w = (const float*)d_in[15];
  const float* ln2b = (const float*)d_in[16];
  const float* fW1  = (const float*)d_in[17];
  const float* fb1  = (const float*)d_in[18];
  const float* fW2  = (const float*)d_in[19];
  const float* fb2  = (const float*)d_in[20];
  const float* gW1  = (const float*)d_in[21];
  const float* gb1  = (const float*)d_in[22];
  const float* gW2  = (const float*)d_in[23];
  const float* gb2  = (const float*)d_in[24];
  const float* g2nW = (const float*)d_in[25];
  const float* g2nb = (const float*)d_in[26];
  const float* dW1  = (const float*)d_in[27];
  const float* db1  = (const float*)d_in[28];
  const float* dW2  = (const float*)d_in[29];
  const float* db2  = (const float*)d_in[30];
  float* out = (float*)d_out;

  char* w = (char*)d_ws;
  float*  h    = (float*)w;  w += (size_t)Nn*64*4;
  float*  xl   = (float*)w;  w += (size_t)Nn*256*4;
  float*  xr   = (float*)w;  w += (size_t)Nn*256*4;
  float4* meta = (float4*)w; w += (size_t)Et*16;
  float*  gatv = (float*)w;  w += (size_t)Nn*64*4;
  float* fW1T = (float*)w; w += (size_t)Ll*128*64*4;
  float* gW1T = (float*)w; w += (size_t)Ll*64*64*4;
  float* gate = (float*)w; w += 1024*4;
  float* gsum = (float*)w; w += 1024*4;
  float* gmax = (float*)w; w += 1024*4;
  float* easum  = (float*)w; w += 16;
  float* eamean = (float*)w; w += 16;
  int* deg    = (int*)w; w += (size_t)Nn*4;
  int* indptr = (int*)w; w += (size_t)(Nn+1)*4;
  int* fill   = (int*)w; w += (size_t)Nn*4;
  int* gcnt   = (int*)w; w += 64;

  const int* ei_src = ei;
  const int* ei_dst = ei + Ee;

  k_init   <<<(Nn+255)/256, 256, 0, stream>>>(deg, gsum, gmax, gcnt, easum);
  k_eamean <<<256, 256, 0, stream>>>(ea, easum);
  k_deg    <<<(Et+255)/256, 256, 0, stream>>>(ei_dst, deg);
  k_bcnt   <<<(Nn+255)/256, 256, 0, stream>>>(bat, gcnt);
  k_scan   <<<1, 1024, 0, stream>>>(deg, indptr, fill, easum, eamean);
  k_scatter<<<(Et+255)/256, 256, 0, stream>>>(ei_src, ei_dst, ea, eamean, fill, meta);
  k_tw     <<<(Ll*64*128+255)/256, 256, 0, stream>>>(fW1, gW1, fW1T, gW1T);
  k_enc    <<<(Nn*64+255)/256, 256, 0, stream>>>(x, encW, encb, h);

  for (int l=0; l<Ll; ++l){
    k_xlxr<<<(Nn+31)/32, 256, 0, stream>>>(h, l ? gate : nullptr, bat,
        Wl + (size_t)l*64*256, bl + (size_t)l*256,
        Wr + (size_t)l*64*256, br + (size_t)l*256, xl, xr);
    k_edge<<<Nn/4, 256, 0, stream>>>(xl, xr, indptr, meta,
        We + (size_t)l*3*256, attw + (size_t)l*Hh*64, gatv);
    k_node<<<(Nn+63)/64, 256, 0, stream>>>(h, gatv,
        gatb + (size_t)l*64,
        ln1w + (size_t)l*64, ln1b + (size_t)l*64,
        fW1T + (size_t)l*128*64, fb1 + (size_t)l*128,
        fW2 + (size_t)l*128*64, fb2 + (size_t)l*64,
        ln2w + (size_t)l*64, ln2b + (size_t)l*64,
        gW1T + (size_t)l*64*64, gb1 + (size_t)l*64,
        gW2 + (size_t)l*64*64, gb2 + (size_t)l*64,
        bat, gsum, gmax);
    k_gate<<<1, 1024, 0, stream>>>(gsum, gmax, gcnt,
        g2nW + (size_t)l*128*64, g2nb + (size_t)l*64, gate);
  }

  k_dec<<<Nn/4, 256, 0, stream>>>(h, gate, bat, dW1, db1, dW2, db2, out);
}

// Round 9
// 1756.163 us; speedup vs baseline: 1.2699x; 1.2699x over previous
//
#include <hip/hip_runtime.h>

#define DEV __device__ __forceinline__

constexpr int Nn  = 50000;
constexpr int Ee  = 800000;
constexpr int Et  = 850000;   // E + N self loops
constexpr int Gg  = 16;
constexpr int Dd  = 64;
constexpr int Hh  = 4;
constexpr int Ll  = 4;
constexpr int INd = 7;
constexpr float NEG  = 0.2f;
constexpr float EPSL = 1e-5f;

DEV float lrelu(float x){ return fmaxf(x, NEG*x); }
DEV float wsum64(float v){
  v += __shfl_xor(v,1); v += __shfl_xor(v,2); v += __shfl_xor(v,4);
  v += __shfl_xor(v,8); v += __shfl_xor(v,16); v += __shfl_xor(v,32);
  return v;
}
DEV void atomicMaxF(float* a, float v){
  if (v >= 0.f) atomicMax((int*)a, __float_as_int(v));
  else          atomicMin((unsigned int*)a, __float_as_uint(v));
}

// ---------------- setup kernels ----------------

__global__ void k_init(int* deg, float* g_sum, float* g_max, int* grp_cnt, float* ea_sum){
  int i = blockIdx.x*256 + threadIdx.x;
  if (i < Nn) deg[i] = 0;
  if (i < Gg*Dd){ g_sum[i] = 0.f; g_max[i] = -3.4e38f; }
  if (i < Gg) grp_cnt[i] = 0;
  if (i < 3) ea_sum[i] = 0.f;
}

__global__ void k_eamean(const float* __restrict__ ea, float* __restrict__ ea_sum){
  __shared__ float ps[4][3];
  int tid = threadIdx.x;
  float s0=0.f, s1=0.f, s2=0.f;
  int stride = gridDim.x * blockDim.x;
  for (int i = blockIdx.x*blockDim.x + tid; i < Ee; i += stride){
    s0 += ea[3*i]; s1 += ea[3*i+1]; s2 += ea[3*i+2];
  }
  s0 = wsum64(s0); s1 = wsum64(s1); s2 = wsum64(s2);
  int wid = tid >> 6;
  if ((tid & 63) == 0){ ps[wid][0]=s0; ps[wid][1]=s1; ps[wid][2]=s2; }
  __syncthreads();
  if (tid == 0){
    atomicAdd(ea_sum+0, ps[0][0]+ps[1][0]+ps[2][0]+ps[3][0]);
    atomicAdd(ea_sum+1, ps[0][1]+ps[1][1]+ps[2][1]+ps[3][1]);
    atomicAdd(ea_sum+2, ps[0][2]+ps[1][2]+ps[2][2]+ps[3][2]);
  }
}

__global__ void k_deg(const int* __restrict__ ei_dst, int* __restrict__ deg){
  int e = blockIdx.x*256 + threadIdx.x;
  if (e >= Et) return;
  int dst = (e < Ee) ? ei_dst[e] : (e - Ee);
  atomicAdd(&deg[dst], 1);
}

__global__ void k_bcnt(const int* __restrict__ batch, int* __restrict__ grp_cnt){
  __shared__ int c[Gg];
  if (threadIdx.x < Gg) c[threadIdx.x] = 0;
  __syncthreads();
  int i = blockIdx.x*256 + threadIdx.x;
  if (i < Nn) atomicAdd(&c[batch[i]], 1);
  __syncthreads();
  if (threadIdx.x < Gg && c[threadIdx.x]) atomicAdd(&grp_cnt[threadIdx.x], c[threadIdx.x]);
}

__global__ __launch_bounds__(1024) void k_scan(
    const int* __restrict__ deg, int* __restrict__ indptr, int* __restrict__ fill,
    const float* __restrict__ ea_sum, float* __restrict__ ea_mean)
{
  __shared__ int tot[1024];
  int tid = threadIdx.x;
  if (tid < 3) ea_mean[tid] = ea_sum[tid] * (1.f/(float)Ee);
  constexpr int CH = (Nn + 1023)/1024;   // 49
  int b0 = tid*CH;
  int loc[CH];
  int s = 0;
  #pragma unroll
  for (int i=0;i<CH;++i){
    int idx = b0+i;
    int d = (idx < Nn) ? deg[idx] : 0;
    loc[i] = s; s += d;
  }
  tot[tid] = s;
  __syncthreads();
  for (int off=1; off<1024; off<<=1){
    int v = (tid>=off) ? tot[tid-off] : 0;
    __syncthreads();
    tot[tid] += v;
    __syncthreads();
  }
  int base = (tid==0) ? 0 : tot[tid-1];
  #pragma unroll
  for (int i=0;i<CH;++i){
    int idx = b0+i;
    if (idx < Nn){
      int ex = base + loc[i];
      fill[idx] = ex;
      indptr[idx+1] = ex + deg[idx];
    }
  }
  if (tid==0) indptr[0] = 0;
}

// scatter edge meta {src, a0, a1, a2} into CSR slots (self-loop attrs = ea_mean)
__global__ void k_scatter(const int* __restrict__ ei_src, const int* __restrict__ ei_dst,
                          const float* __restrict__ ea, const float* __restrict__ ea_mean,
                          int* __restrict__ fill, float4* __restrict__ meta){
  int e = blockIdx.x*256 + threadIdx.x;
  if (e >= Et) return;
  int src, dst; float a0, a1, a2;
  if (e < Ee){
    src = ei_src[e]; dst = ei_dst[e];
    a0 = ea[3*e]; a1 = ea[3*e+1]; a2 = ea[3*e+2];
  } else {
    src = dst = e - Ee;
    a0 = ea_mean[0]; a1 = ea_mean[1]; a2 = ea_mean[2];
  }
  int pos = atomicAdd(&fill[dst], 1);
  meta[pos] = make_float4(__int_as_float(src), a0, a1, a2);
}

// transpose fW1 (L x 64 x 128 -> L x 128 x 64) and gW1 (L x 64 x 64 -> T)
__global__ void k_tw(const float* __restrict__ fW1, const float* __restrict__ gW1,
                     float* __restrict__ fW1T, float* __restrict__ gW1T){
  int i = blockIdx.x*256 + threadIdx.x;
  if (i < Ll*64*128){
    int l = i >> 13, r = (i >> 7) & 63, c = i & 127;
    fW1T[l*8192 + c*64 + r] = fW1[i];
  }
  if (i < Ll*64*64){
    int l = i >> 12, r = (i >> 6) & 63, c = i & 63;
    gW1T[l*4096 + c*64 + r] = gW1[i];
  }
}

// ---------------- encoder ----------------

__global__ __launch_bounds__(256) void k_enc(
    const float* __restrict__ x, const float* __restrict__ W, const float* __restrict__ b,
    float* __restrict__ h)
{
  int i = blockIdx.x*256 + threadIdx.x;
  if (i >= Nn*Dd) return;
  int n = i >> 6, d = i & 63;
  float s = b[d];
  #pragma unroll
  for (int k=0;k<INd;++k) s = fmaf(x[n*INd+k], W[k*Dd+d], s);
  h[i] = s;
}

// ---------------- xl/xr GEMM (+ gate apply from previous layer) ----------------

__global__ __launch_bounds__(256) void k_xlxr(
    float* __restrict__ h, const float* __restrict__ gate, const int* __restrict__ batch,
    const float* __restrict__ Wl, const float* __restrict__ bl,
    const float* __restrict__ Wr, const float* __restrict__ br,
    float* __restrict__ xl, float* __restrict__ xr)
{
  __shared__ float lh[32*68];
  int tid = threadIdx.x;
  int n0 = blockIdx.x * 32;
  for (int r=0; r<8; ++r){
    int idx = r*256 + tid;
    int nl = idx >> 6, d = idx & 63;
    int node = n0 + nl;
    float v = 0.f;
    if (node < Nn){
      v = h[(size_t)node*64 + d];
      if (gate){ v *= gate[batch[node]*64 + d]; h[(size_t)node*64 + d] = v; }
    }
    lh[nl*68 + d] = v;
  }
  __syncthreads();
  int lane = tid & 63;
  int nb = (tid >> 6) * 8;
  int c0 = lane * 8;
  const float* W; const float* bb; float* outp; int col;
  if (c0 < 256){ W = Wl; bb = bl; outp = xl; col = c0; }
  else         { W = Wr; bb = br; outp = xr; col = c0 - 256; }
  float4 bA = *reinterpret_cast<const float4*>(bb + col);
  float4 bB = *reinterpret_cast<const float4*>(bb + col + 4);
  float acc[8][8];
  #pragma unroll
  for (int nq=0; nq<8; ++nq){
    acc[nq][0]=bA.x; acc[nq][1]=bA.y; acc[nq][2]=bA.z; acc[nq][3]=bA.w;
    acc[nq][4]=bB.x; acc[nq][5]=bB.y; acc[nq][6]=bB.z; acc[nq][7]=bB.w;
  }
  for (int d=0; d<64; d+=4){
    float4 wA[4], wB[4];
    #pragma unroll
    for (int dq=0; dq<4; ++dq){
      wA[dq] = *reinterpret_cast<const float4*>(W + (d+dq)*256 + col);
      wB[dq] = *reinterpret_cast<const float4*>(W + (d+dq)*256 + col + 4);
    }
    #pragma unroll
    for (int nq=0; nq<8; ++nq){
      float4 hv = *reinterpret_cast<const float4*>(&lh[(nb+nq)*68 + d]);
      #pragma unroll
      for (int dq=0; dq<4; ++dq){
        float hh = (dq==0)? hv.x : (dq==1)? hv.y : (dq==2)? hv.z : hv.w;
        acc[nq][0] = fmaf(hh, wA[dq].x, acc[nq][0]);
        acc[nq][1] = fmaf(hh, wA[dq].y, acc[nq][1]);
        acc[nq][2] = fmaf(hh, wA[dq].z, acc[nq][2]);
        acc[nq][3] = fmaf(hh, wA[dq].w, acc[nq][3]);
        acc[nq][4] = fmaf(hh, wB[dq].x, acc[nq][4]);
        acc[nq][5] = fmaf(hh, wB[dq].y, acc[nq][5]);
        acc[nq][6] = fmaf(hh, wB[dq].z, acc[nq][6]);
        acc[nq][7] = fmaf(hh, wB[dq].w, acc[nq][7]);
      }
    }
  }
  #pragma unroll
  for (int nq=0; nq<8; ++nq){
    int node = n0 + nb + nq;
    if (node < Nn){
      float4 oA = make_float4(acc[nq][0],acc[nq][1],acc[nq][2],acc[nq][3]);
      float4 oB = make_float4(acc[nq][4],acc[nq][5],acc[nq][6],acc[nq][7]);
      *reinterpret_cast<float4*>(outp + (size_t)node*256 + col)     = oA;
      *reinterpret_cast<float4*>(outp + (size_t)node*256 + col + 4) = oB;
    }
  }
}

// ---------------- edge phase: GATv2 attention aggregation ----------------

__global__ __launch_bounds__(256) void k_edge(
    const float* __restrict__ xl, const float* __restrict__ xr,
    const int* __restrict__ indptr, const float4* __restrict__ meta,
    const float* __restrict__ We, const float* __restrict__ att,
    float* __restrict__ gat_out)
{
  int lane = threadIdx.x & 63;
  int n = __builtin_amdgcn_readfirstlane(blockIdx.x*4 + (threadIdx.x>>6));
  int coff = (lane>>4)*64 + (lane & 15)*4;

  const float4 xr4 = *reinterpret_cast<const float4*>(xr + (size_t)n*256 + coff);
  const float4 we0 = *reinterpret_cast<const float4*>(We + 0*256 + coff);
  const float4 we1 = *reinterpret_cast<const float4*>(We + 1*256 + coff);
  const float4 we2 = *reinterpret_cast<const float4*>(We + 2*256 + coff);
  const float4 aw  = *reinterpret_cast<const float4*>(att + coff);

  int p0 = __builtin_amdgcn_readfirstlane(indptr[n]);
  int p1 = __builtin_amdgcn_readfirstlane(indptr[n+1]);
  int cnt = p1 - p0;                       // >= 1 (self loop)
  const float4* __restrict__ mp = meta + p0;
  int lane7 = lane & 7;
  int ntiles = (cnt + 7) >> 3;

  float den = 0.f, a0c=0.f, a1c=0.f, a2c=0.f, a3c=0.f;

  auto ldm = [&](int t) -> float4 {
    int idx = t*8 + lane7;
    idx = idx < cnt-1 ? idx : cnt-1;
    return mp[idx];
  };
  auto issueXv = [&](const float4& mb, float4 (&xv)[8]){
    #pragma unroll
    for (int i=0;i<8;++i){
      int s = __float_as_int(__shfl(mb.x, i));
      xv[i] = *reinterpret_cast<const float4*>(xl + (size_t)s*256 + coff);
    }
  };
  auto compute = [&](const float4& mb, const float4 (&xv)[8], int t){
    #pragma unroll
    for (int i=0;i<8;++i){
      float a0 = __shfl(mb.y, i), a1 = __shfl(mb.z, i), a2 = __shfl(mb.w, i);
      float t0 = fmaf(a0, we0.x, xr4.x); t0 = fmaf(a1, we1.x, t0); t0 = fmaf(a2, we2.x, t0);
      float t1 = fmaf(a0, we0.y, xr4.y); t1 = fmaf(a1, we1.y, t1); t1 = fmaf(a2, we2.y, t1);
      float t2 = fmaf(a0, we0.z, xr4.z); t2 = fmaf(a1, we1.z, t2); t2 = fmaf(a2, we2.z, t2);
      float t3 = fmaf(a0, we0.w, xr4.w); t3 = fmaf(a1, we1.w, t3); t3 = fmaf(a2, we2.w, t3);
      float u0 = lrelu(xv[i].x + t0), u1 = lrelu(xv[i].y + t1);
      float u2 = lrelu(xv[i].z + t2), u3 = lrelu(xv[i].w + t3);
      float part = fmaf(u0, aw.x, fmaf(u1, aw.y, fmaf(u2, aw.z, u3*aw.w)));
      part += __shfl_xor(part,1); part += __shfl_xor(part,2);
      part += __shfl_xor(part,4); part += __shfl_xor(part,8);
      float w = (t*8 + i < cnt) ? __expf(part) : 0.f;   // logits tiny: no max needed
      den += w;
      a0c = fmaf(w, xv[i].x, a0c);
      a1c = fmaf(w, xv[i].y, a1c);
      a2c = fmaf(w, xv[i].z, a2c);
      a3c = fmaf(w, xv[i].w, a3c);
    }
  };

  float4 xvA[8], xvB[8];
  float4 mCur = ldm(0);
  float4 mNxt = (ntiles > 1) ? ldm(1) : mCur;
  float4 mN2  = mCur;
  issueXv(mCur, xvA);

  int t = 0;
  while (true){
    if (t+2 < ntiles) mN2 = ldm(t+2);
    if (t+1 < ntiles) issueXv(mNxt, xvB);
    compute(mCur, xvA, t);
    if (t+1 >= ntiles) break;
    if (t+3 < ntiles) mCur = ldm(t+3);
    if (t+2 < ntiles) issueXv(mN2, xvA);
    compute(mNxt, xvB, t+1);
    if (t+2 >= ntiles) break;
    float4 tm = mCur; mCur = mN2; mNxt = tm;
    t += 2;
  }

  float inv = 1.f/(den*(float)Hh);
  float s0=a0c*inv, s1=a1c*inv, s2=a2c*inv, s3=a3c*inv;
  s0 += __shfl_xor(s0,16); s0 += __shfl_xor(s0,32);
  s1 += __shfl_xor(s1,16); s1 += __shfl_xor(s1,32);
  s2 += __shfl_xor(s2,16); s2 += __shfl_xor(s2,32);
  s3 += __shfl_xor(s3,16); s3 += __shfl_xor(s3,32);
  int srcl = lane >> 2;
  float w0 = __shfl(s0, srcl), w1 = __shfl(s1, srcl);
  float w2 = __shfl(s2, srcl), w3 = __shfl(s3, srcl);
  int kk = lane & 3;
  float gat = (kk==0)? w0 : (kk==1)? w1 : (kk==2)? w2 : w3;
  gat_out[(size_t)n*64 + lane] = gat;
}

// ---------------- node phase v5: lane = node, LDS-staged weights ----------------
// Block = 256 = 4 independent waves x 64 DISTINCT nodes (no partial sums, no
// redundant work). Weights staged in LDS once per block; weight reads are
// lane-uniform ds_read_b128 broadcasts (conflict-free, no cache misses, compiler
// pipelines next col under current col's FMAs). Latent weights restaged into the
// same 64KB buffer; buffer finally reused as 4x rotation-swizzled transpose tiles.

__global__ __launch_bounds__(256) void k_node(
    float* __restrict__ h, const float* __restrict__ gat,
    const float* __restrict__ gatb,
    const float* __restrict__ ln1w, const float* __restrict__ ln1b,
    const float* __restrict__ fW1T, const float* __restrict__ fb1,
    const float* __restrict__ fW2,  const float* __restrict__ fb2,
    const float* __restrict__ ln2w, const float* __restrict__ ln2b,
    const float* __restrict__ gW1T, const float* __restrict__ gb1,
    const float* __restrict__ gW2,  const float* __restrict__ gb2,
    const int* __restrict__ batch, float* __restrict__ g_sum, float* __restrict__ g_max)
{
  __shared__ float4 sW4[4096];   // 64KB: {W1T|W2} -> {gW1T|gW2} -> 4x [64][64] transpose tiles
  __shared__ int    sB[256];
  float* sW = reinterpret_cast<float*>(sW4);
  int tid  = threadIdx.x;
  int lane = tid & 63;
  int wv   = tid >> 6;
  int n = blockIdx.x*256 + wv*64 + lane;
  bool valid = n < Nn;
  sB[tid] = valid ? batch[n] : -1;

  // cooperative stage of FFN weights (W1T 8192f, W2 8192f)
  {
    const float4* s1 = reinterpret_cast<const float4*>(fW1T);
    const float4* s2 = reinterpret_cast<const float4*>(fW2);
    for (int k=tid; k<2048; k+=256) sW4[k] = s1[k];
    for (int k=tid; k<2048; k+=256) sW4[2048+k] = s2[k];
  }

  // x = h[n] + gat[n] + gatb  (independent of staging; overlaps it)
  float x[64];
  if (valid){
    #pragma unroll
    for (int q=0; q<16; ++q){
      float4 a = *reinterpret_cast<const float4*>(h   + (size_t)n*64 + q*4);
      float4 b = *reinterpret_cast<const float4*>(gat + (size_t)n*64 + q*4);
      float4 g = *reinterpret_cast<const float4*>(gatb + q*4);
      x[q*4+0] = a.x + b.x + g.x;
      x[q*4+1] = a.y + b.y + g.y;
      x[q*4+2] = a.z + b.z + g.z;
      x[q*4+3] = a.w + b.w + g.w;
    }
  } else {
    #pragma unroll
    for (int d=0; d<64; ++d) x[d] = 0.f;
  }

  // LN1 (in-lane)
  {
    float s0=0,s1=0,s2=0,s3=0;
    #pragma unroll
    for (int d=0; d<64; d+=4){ s0+=x[d]; s1+=x[d+1]; s2+=x[d+2]; s3+=x[d+3]; }
    float mean = ((s0+s1)+(s2+s3)) * (1.f/64.f);
    float v0=0,v1=0,v2=0,v3=0;
    #pragma unroll
    for (int d=0; d<64; d+=4){
      float a=x[d]-mean, b=x[d+1]-mean, c=x[d+2]-mean, e=x[d+3]-mean;
      v0=fmaf(a,a,v0); v1=fmaf(b,b,v1); v2=fmaf(c,c,v2); v3=fmaf(e,e,v3);
    }
    float rstd = rsqrtf(((v0+v1)+(v2+v3))*(1.f/64.f) + EPSL);
    #pragma unroll
    for (int d=0; d<64; ++d) x[d] = (x[d]-mean)*rstd*ln1w[d] + ln1b[d];
  }
  __syncthreads();

  // FFN: o[j] = fb2[j] + sum_c lrelu(x.W1T[c] + fb1[c]) * W2[c][j]
  float o[64];
  #pragma unroll
  for (int j=0; j<64; ++j) o[j] = fb2[j];
  #pragma unroll 2
  for (int c=0; c<128; ++c){
    const float* w1 = sW + c*64;
    float a0=0,a1=0,a2=0,a3=0;
    #pragma unroll
    for (int d=0; d<64; d+=4){
      float4 wv4 = *reinterpret_cast<const float4*>(&w1[d]);
      a0 = fmaf(x[d],   wv4.x, a0);
      a1 = fmaf(x[d+1], wv4.y, a1);
      a2 = fmaf(x[d+2], wv4.z, a2);
      a3 = fmaf(x[d+3], wv4.w, a3);
    }
    float hc = lrelu((a0+a1)+(a2+a3) + fb1[c]);
    const float* w2 = sW + 8192 + c*64;
    #pragma unroll
    for (int j=0; j<64; j+=4){
      float4 wv4 = *reinterpret_cast<const float4*>(&w2[j]);
      o[j]   = fmaf(hc, wv4.x, o[j]);
      o[j+1] = fmaf(hc, wv4.y, o[j+1]);
      o[j+2] = fmaf(hc, wv4.z, o[j+2]);
      o[j+3] = fmaf(hc, wv4.w, o[j+3]);
    }
  }
  __syncthreads();

  // restage latent weights (gW1T 4096f, gW2 4096f); LN2 overlaps the stores
  {
    const float4* s1 = reinterpret_cast<const float4*>(gW1T);
    const float4* s2 = reinterpret_cast<const float4*>(gW2);
    for (int k=tid; k<1024; k+=256) sW4[k] = s1[k];
    for (int k=tid; k<1024; k+=256) sW4[1024+k] = s2[k];
  }
  // residual + LN2 -> hn (in x); store h
  {
    #pragma unroll
    for (int d=0; d<64; ++d) x[d] += o[d];
    float s0=0,s1=0,s2=0,s3=0;
    #pragma unroll
    for (int d=0; d<64; d+=4){ s0+=x[d]; s1+=x[d+1]; s2+=x[d+2]; s3+=x[d+3]; }
    float mean = ((s0+s1)+(s2+s3)) * (1.f/64.f);
    float v0=0,v1=0,v2=0,v3=0;
    #pragma unroll
    for (int d=0; d<64; d+=4){
      float a=x[d]-mean, b=x[d+1]-mean, c=x[d+2]-mean, e=x[d+3]-mean;
      v0=fmaf(a,a,v0); v1=fmaf(b,b,v1); v2=fmaf(c,c,v2); v3=fmaf(e,e,v3);
    }
    float rstd = rsqrtf(((v0+v1)+(v2+v3))*(1.f/64.f) + EPSL);
    #pragma unroll
    for (int d=0; d<64; ++d) x[d] = (x[d]-mean)*rstd*ln2w[d] + ln2b[d];
    if (valid){
      #pragma unroll
      for (int q=0; q<16; ++q){
        *reinterpret_cast<float4*>(h + (size_t)n*64 + q*4) =
            make_float4(x[q*4], x[q*4+1], x[q*4+2], x[q*4+3]);
      }
    }
  }
  __syncthreads();

  // latent: lat[j] = gb2[j] + sum_c lrelu(x.gW1T[c] + gb1[c]) * gW2[c][j]
  #pragma unroll
  for (int j=0; j<64; ++j) o[j] = gb2[j];
  #pragma unroll 2
  for (int c=0; c<64; ++c){
    const float* w1 = sW + c*64;
    float a0=0,a1=0,a2=0,a3=0;
    #pragma unroll
    for (int d=0; d<64; d+=4){
      float4 wv4 = *reinterpret_cast<const float4*>(&w1[d]);
      a0 = fmaf(x[d],   wv4.x, a0);
      a1 = fmaf(x[d+1], wv4.y, a1);
      a2 = fmaf(x[d+2], wv4.z, a2);
      a3 = fmaf(x[d+3], wv4.w, a3);
    }
    float uc = lrelu((a0+a1)+(a2+a3) + gb1[c]);
    const float* w2 = sW + 4096 + c*64;
    #pragma unroll
    for (int j=0; j<64; j+=4){
      float4 wv4 = *reinterpret_cast<const float4*>(&w2[j]);
      o[j]   = fmaf(uc, wv4.x, o[j]);
      o[j+1] = fmaf(uc, wv4.y, o[j+1]);
      o[j+2] = fmaf(uc, wv4.z, o[j+2]);
      o[j+3] = fmaf(uc, wv4.w, o[j+3]);
    }
  }
  __syncthreads();   // all waves done reading latent weights; buffer reused below

  // rotation-swizzled transpose tile per wave ([64][64], col=(lane+j)&63 -> <=2-way banks)
  float* sT = sW + wv*4096;
  #pragma unroll
  for (int j=0; j<64; ++j) sT[j*64 + ((lane+j)&63)] = o[j];
  // sorted-run group atomics: lane = dim, iterate this wave's 64 nodes
  {
    int cur = -1; float acc = 0.f, mx = -3.4e38f;
    for (int nn=0; nn<64; ++nn){
      int gv = sB[wv*64 + nn];
      float v = sT[lane*64 + ((nn+lane)&63)];
      if (gv != cur){
        if (cur >= 0){
          atomicAdd(g_sum + cur*64 + lane, acc);
          atomicMaxF(g_max + cur*64 + lane, mx);
        }
        cur = gv; acc = 0.f; mx = -3.4e38f;
      }
      if (gv >= 0){ acc += v; mx = fmaxf(mx, v); }
    }
    if (cur >= 0){
      atomicAdd(g_sum + cur*64 + lane, acc);
      atomicMaxF(g_max + cur*64 + lane, mx);
    }
  }
}

// ---------------- gate (one block), also resets accumulators ----------------

__global__ __launch_bounds__(1024) void k_gate(
    float* __restrict__ g_sum, float* __restrict__ g_max, const int* __restrict__ grp_cnt,
    const float* __restrict__ gW, const float* __restrict__ gb, float* __restrict__ gate)
{
  __shared__ float sme[Gg*64];
  __shared__ float smx[Gg*64];
  int tid = threadIdx.x;
  int g = tid >> 6, d = tid & 63;
  float cnt = fmaxf((float)grp_cnt[g], 1.f);
  sme[tid] = g_sum[tid] / cnt;
  smx[tid] = g_max[tid];
  __syncthreads();
  float a = gb[d];
  #pragma unroll
  for (int j=0;j<64;++j){
    a = fmaf(sme[g*64+j], gW[j*64+d],      a);
    a = fmaf(smx[g*64+j], gW[(64+j)*64+d], a);
  }
  gate[tid] = 1.f/(1.f + __expf(-a));
  g_sum[tid] = 0.f;
  g_max[tid] = -3.4e38f;
}

// ---------------- decoder (applies final gate) ----------------

__global__ __launch_bounds__(256) void k_dec(
    const float* __restrict__ h, const float* __restrict__ gate, const int* __restrict__ batch,
    const float* __restrict__ W1, const float* __restrict__ b1,
    const float* __restrict__ W2, const float* __restrict__ b2,
    float* __restrict__ out)
{
  int lane = threadIdx.x & 63;
  int n = __builtin_amdgcn_readfirstlane(blockIdx.x*4 + (threadIdx.x>>6));
  float hv = h[(size_t)n*64 + lane] * gate[batch[n]*64 + lane];
  float hid = b1[lane];
  #pragma unroll
  for (int d2=0; d2<64; ++d2) hid = fmaf(__shfl(hv,d2), W1[d2*64+lane], hid);
  hid = lrelu(hid);
  float r0 = wsum64(hid * W2[lane*2+0]);
  float r1 = wsum64(hid * W2[lane*2+1]);
  if (lane == 0){
    out[(size_t)n*2]   = r0 + b2[0];
    out[(size_t)n*2+1] = r1 + b2[1];
  }
}

// ---------------- launch ----------------

extern "C" void kernel_launch(void* const* d_in, const int* in_sizes, int n_in,
                              void* d_out, int out_size, void* d_ws, size_t ws_size,
                              hipStream_t stream) {
  const float* x    = (const float*)d_in[0];
  const float* ea   = (const float*)d_in[1];
  const int*   ei   = (const int*)  d_in[2];
  const int*   bat  = (const int*)  d_in[3];
  const float* encW = (const float*)d_in[4];
  const float* encb = (const float*)d_in[5];
  const float* Wl   = (const float*)d_in[6];
  const float* bl   = (const float*)d_in[7];
  const float* Wr   = (const float*)d_in[8];
  const float* br   = (const float*)d_in[9];
  const float* We   = (const float*)d_in[10];
  const float* attw = (const float*)d_in[11];
  const float* gatb = (const float*)d_in[12];
  const float* ln1w = (const float*)d_in[13];
  const float* ln1b = (const float*)d_in[14];
  const float* ln2w = (const float*)d_in[15];
  const float* ln2b = (const float*)d_in[16];
  const float* fW1  = (const float*)d_in[17];
  const float* fb1  = (const float*)d_in[18];
  const float* fW2  = (const float*)d_in[19];
  const float* fb2  = (const float*)d_in[20];
  const float* gW1  = (const float*)d_in[21];
  const float* gb1  = (const float*)d_in[22];
  const float* gW2  = (const float*)d_in[23];
  const float* gb2  = (const float*)d_in[24];
  const float* g2nW = (const float*)d_in[25];
  const float* g2nb = (const float*)d_in[26];
  const float* dW1  = (const float*)d_in[27];
  const float* db1  = (const float*)d_in[28];
  const float* dW2  = (const float*)d_in[29];
  const float* db2  = (const float*)d_in[30];
  float* out = (float*)d_out;

  char* w = (char*)d_ws;
  float*  h    = (float*)w;  w += (size_t)Nn*64*4;
  float*  xl   = (float*)w;  w += (size_t)Nn*256*4;
  float*  xr   = (float*)w;  w += (size_t)Nn*256*4;
  float4* meta = (float4*)w; w += (size_t)Et*16;
  float*  gatv = (float*)w;  w += (size_t)Nn*64*4;
  float* fW1T = (float*)w; w += (size_t)Ll*128*64*4;
  float* gW1T = (float*)w; w += (size_t)Ll*64*64*4;
  float* gate = (float*)w; w += 1024*4;
  float* gsum = (float*)w; w += 1024*4;
  float* gmax = (float*)w; w += 1024*4;
  float* easum  = (float*)w; w += 16;
  float* eamean = (float*)w; w += 16;
  int* deg    = (int*)w; w += (size_t)Nn*4;
  int* indptr = (int*)w; w += (size_t)(Nn+1)*4;
  int* fill   = (int*)w; w += (size_t)Nn*4;
  int* gcnt   = (int*)w; w += 64;

  const int* ei_src = ei;
  const int* ei_dst = ei + Ee;

  k_init   <<<(Nn+255)/256, 256, 0, stream>>>(deg, gsum, gmax, gcnt, easum);
  k_eamean <<<256, 256, 0, stream>>>(ea, easum);
  k_deg    <<<(Et+255)/256, 256, 0, stream>>>(ei_dst, deg);
  k_bcnt   <<<(Nn+255)/256, 256, 0, stream>>>(bat, gcnt);
  k_scan   <<<1, 1024, 0, stream>>>(deg, indptr, fill, easum, eamean);
  k_scatter<<<(Et+255)/256, 256, 0, stream>>>(ei_src, ei_dst, ea, eamean, fill, meta);
  k_tw     <<<(Ll*64*128+255)/256, 256, 0, stream>>>(fW1, gW1, fW1T, gW1T);
  k_enc    <<<(Nn*64+255)/256, 256, 0, stream>>>(x, encW, encb, h);

  for (int l=0; l<Ll; ++l){
    k_xlxr<<<(Nn+31)/32, 256, 0, stream>>>(h, l ? gate : nullptr, bat,
        Wl + (size_t)l*64*256, bl + (size_t)l*256,
        Wr + (size_t)l*64*256, br + (size_t)l*256, xl, xr);
    k_edge<<<Nn/4, 256, 0, stream>>>(xl, xr, indptr, meta,
        We + (size_t)l*3*256, attw + (size_t)l*Hh*64, gatv);
    k_node<<<(Nn+255)/256, 256, 0, stream>>>(h, gatv,
        gatb + (size_t)l*64,
        ln1w + (size_t)l*64, ln1b + (size_t)l*64,
        fW1T + (size_t)l*128*64, fb1 + (size_t)l*128,
        fW2 + (size_t)l*128*64, fb2 + (size_t)l*64,
        ln2w + (size_t)l*64, ln2b + (size_t)l*64,
        gW1T + (size_t)l*64*64, gb1 + (size_t)l*64,
        gW2 + (size_t)l*64*64, gb2 + (size_t)l*64,
        bat, gsum, gmax);
    k_gate<<<1, 1024, 0, stream>>>(gsum, gmax, gcnt,
        g2nW + (size_t)l*128*64, g2nb + (size_t)l*64, gate);
  }

  k_dec<<<Nn/4, 256, 0, stream>>>(h, gate, bat, dW1, db1, dW2, db2, out);
}

// Round 10
// 1563.045 us; speedup vs baseline: 1.4268x; 1.1236x over previous
//
#include <hip/hip_runtime.h>

#define DEV __device__ __forceinline__

constexpr int Nn  = 50000;
constexpr int Ee  = 800000;
constexpr int Et  = 850000;   // E + N self loops
constexpr int Gg  = 16;
constexpr int Dd  = 64;
constexpr int Hh  = 4;
constexpr int Ll  = 4;
constexpr int INd = 7;
constexpr float NEG  = 0.2f;
constexpr float EPSL = 1e-5f;

DEV float lrelu(float x){ return fmaxf(x, NEG*x); }
DEV float wsum64(float v){
  v += __shfl_xor(v,1); v += __shfl_xor(v,2); v += __shfl_xor(v,4);
  v += __shfl_xor(v,8); v += __shfl_xor(v,16); v += __shfl_xor(v,32);
  return v;
}
DEV void atomicMaxF(float* a, float v){
  if (v >= 0.f) atomicMax((int*)a, __float_as_int(v));
  else          atomicMin((unsigned int*)a, __float_as_uint(v));
}
// fp32 -> bf16 with round-to-nearest-even
DEV unsigned short f2bf(float f){
  unsigned int u = __float_as_uint(f);
  unsigned int r = (u + 0x7FFFu + ((u >> 16) & 1u)) >> 16;
  return (unsigned short)r;
}
DEV float bf2f(unsigned short b){
  return __uint_as_float(((unsigned int)b) << 16);
}

// ---------------- setup kernels ----------------

__global__ void k_init(int* deg, float* g_sum, float* g_max, int* grp_cnt, float* ea_sum){
  int i = blockIdx.x*256 + threadIdx.x;
  if (i < Nn) deg[i] = 0;
  if (i < Gg*Dd){ g_sum[i] = 0.f; g_max[i] = -3.4e38f; }
  if (i < Gg) grp_cnt[i] = 0;
  if (i < 3) ea_sum[i] = 0.f;
}

__global__ void k_eamean(const float* __restrict__ ea, float* __restrict__ ea_sum){
  __shared__ float ps[4][3];
  int tid = threadIdx.x;
  float s0=0.f, s1=0.f, s2=0.f;
  int stride = gridDim.x * blockDim.x;
  for (int i = blockIdx.x*blockDim.x + tid; i < Ee; i += stride){
    s0 += ea[3*i]; s1 += ea[3*i+1]; s2 += ea[3*i+2];
  }
  s0 = wsum64(s0); s1 = wsum64(s1); s2 = wsum64(s2);
  int wid = tid >> 6;
  if ((tid & 63) == 0){ ps[wid][0]=s0; ps[wid][1]=s1; ps[wid][2]=s2; }
  __syncthreads();
  if (tid == 0){
    atomicAdd(ea_sum+0, ps[0][0]+ps[1][0]+ps[2][0]+ps[3][0]);
    atomicAdd(ea_sum+1, ps[0][1]+ps[1][1]+ps[2][1]+ps[3][1]);
    atomicAdd(ea_sum+2, ps[0][2]+ps[1][2]+ps[2][2]+ps[3][2]);
  }
}

__global__ void k_deg(const int* __restrict__ ei_dst, int* __restrict__ deg){
  int e = blockIdx.x*256 + threadIdx.x;
  if (e >= Et) return;
  int dst = (e < Ee) ? ei_dst[e] : (e - Ee);
  atomicAdd(&deg[dst], 1);
}

__global__ void k_bcnt(const int* __restrict__ batch, int* __restrict__ grp_cnt){
  __shared__ int c[Gg];
  if (threadIdx.x < Gg) c[threadIdx.x] = 0;
  __syncthreads();
  int i = blockIdx.x*256 + threadIdx.x;
  if (i < Nn) atomicAdd(&c[batch[i]], 1);
  __syncthreads();
  if (threadIdx.x < Gg && c[threadIdx.x]) atomicAdd(&grp_cnt[threadIdx.x], c[threadIdx.x]);
}

__global__ __launch_bounds__(1024) void k_scan(
    const int* __restrict__ deg, int* __restrict__ indptr, int* __restrict__ fill,
    const float* __restrict__ ea_sum, float* __restrict__ ea_mean)
{
  __shared__ int tot[1024];
  int tid = threadIdx.x;
  if (tid < 3) ea_mean[tid] = ea_sum[tid] * (1.f/(float)Ee);
  constexpr int CH = (Nn + 1023)/1024;   // 49
  int b0 = tid*CH;
  int loc[CH];
  int s = 0;
  #pragma unroll
  for (int i=0;i<CH;++i){
    int idx = b0+i;
    int d = (idx < Nn) ? deg[idx] : 0;
    loc[i] = s; s += d;
  }
  tot[tid] = s;
  __syncthreads();
  for (int off=1; off<1024; off<<=1){
    int v = (tid>=off) ? tot[tid-off] : 0;
    __syncthreads();
    tot[tid] += v;
    __syncthreads();
  }
  int base = (tid==0) ? 0 : tot[tid-1];
  #pragma unroll
  for (int i=0;i<CH;++i){
    int idx = b0+i;
    if (idx < Nn){
      int ex = base + loc[i];
      fill[idx] = ex;
      indptr[idx+1] = ex + deg[idx];
    }
  }
  if (tid==0) indptr[0] = 0;
}

// scatter edge meta {src, a0, a1, a2} into CSR slots (self-loop attrs = ea_mean)
__global__ void k_scatter(const int* __restrict__ ei_src, const int* __restrict__ ei_dst,
                          const float* __restrict__ ea, const float* __restrict__ ea_mean,
                          int* __restrict__ fill, float4* __restrict__ meta){
  int e = blockIdx.x*256 + threadIdx.x;
  if (e >= Et) return;
  int src, dst; float a0, a1, a2;
  if (e < Ee){
    src = ei_src[e]; dst = ei_dst[e];
    a0 = ea[3*e]; a1 = ea[3*e+1]; a2 = ea[3*e+2];
  } else {
    src = dst = e - Ee;
    a0 = ea_mean[0]; a1 = ea_mean[1]; a2 = ea_mean[2];
  }
  int pos = atomicAdd(&fill[dst], 1);
  meta[pos] = make_float4(__int_as_float(src), a0, a1, a2);
}

// transpose fW1 (L x 64 x 128 -> L x 128 x 64) and gW1 (L x 64 x 64 -> T)
__global__ void k_tw(const float* __restrict__ fW1, const float* __restrict__ gW1,
                     float* __restrict__ fW1T, float* __restrict__ gW1T){
  int i = blockIdx.x*256 + threadIdx.x;
  if (i < Ll*64*128){
    int l = i >> 13, r = (i >> 7) & 63, c = i & 127;
    fW1T[l*8192 + c*64 + r] = fW1[i];
  }
  if (i < Ll*64*64){
    int l = i >> 12, r = (i >> 6) & 63, c = i & 63;
    gW1T[l*4096 + c*64 + r] = gW1[i];
  }
}

// ---------------- encoder ----------------

__global__ __launch_bounds__(256) void k_enc(
    const float* __restrict__ x, const float* __restrict__ W, const float* __restrict__ b,
    float* __restrict__ h)
{
  int i = blockIdx.x*256 + threadIdx.x;
  if (i >= Nn*Dd) return;
  int n = i >> 6, d = i & 63;
  float s = b[d];
  #pragma unroll
  for (int k=0;k<INd;++k) s = fmaf(x[n*INd+k], W[k*Dd+d], s);
  h[i] = s;
}

// ---------------- xl/xr GEMM (+ gate apply). xl stored as bf16 ----------------

__global__ __launch_bounds__(256) void k_xlxr(
    float* __restrict__ h, const float* __restrict__ gate, const int* __restrict__ batch,
    const float* __restrict__ Wl, const float* __restrict__ bl,
    const float* __restrict__ Wr, const float* __restrict__ br,
    unsigned short* __restrict__ xlb, float* __restrict__ xr)
{
  __shared__ float lh[32*68];
  int tid = threadIdx.x;
  int n0 = blockIdx.x * 32;
  for (int r=0; r<8; ++r){
    int idx = r*256 + tid;
    int nl = idx >> 6, d = idx & 63;
    int node = n0 + nl;
    float v = 0.f;
    if (node < Nn){
      v = h[(size_t)node*64 + d];
      if (gate){ v *= gate[batch[node]*64 + d]; h[(size_t)node*64 + d] = v; }
    }
    lh[nl*68 + d] = v;
  }
  __syncthreads();
  int lane = tid & 63;
  int nb = (tid >> 6) * 8;
  int c0 = lane * 8;
  bool isXl = (c0 < 256);
  const float* W; const float* bb; int col;
  if (isXl){ W = Wl; bb = bl; col = c0; }
  else     { W = Wr; bb = br; col = c0 - 256; }
  float4 bA = *reinterpret_cast<const float4*>(bb + col);
  float4 bB = *reinterpret_cast<const float4*>(bb + col + 4);
  float acc[8][8];
  #pragma unroll
  for (int nq=0; nq<8; ++nq){
    acc[nq][0]=bA.x; acc[nq][1]=bA.y; acc[nq][2]=bA.z; acc[nq][3]=bA.w;
    acc[nq][4]=bB.x; acc[nq][5]=bB.y; acc[nq][6]=bB.z; acc[nq][7]=bB.w;
  }
  for (int d=0; d<64; d+=4){
    float4 wA[4], wB[4];
    #pragma unroll
    for (int dq=0; dq<4; ++dq){
      wA[dq] = *reinterpret_cast<const float4*>(W + (d+dq)*256 + col);
      wB[dq] = *reinterpret_cast<const float4*>(W + (d+dq)*256 + col + 4);
    }
    #pragma unroll
    for (int nq=0; nq<8; ++nq){
      float4 hv = *reinterpret_cast<const float4*>(&lh[(nb+nq)*68 + d]);
      #pragma unroll
      for (int dq=0; dq<4; ++dq){
        float hh = (dq==0)? hv.x : (dq==1)? hv.y : (dq==2)? hv.z : hv.w;
        acc[nq][0] = fmaf(hh, wA[dq].x, acc[nq][0]);
        acc[nq][1] = fmaf(hh, wA[dq].y, acc[nq][1]);
        acc[nq][2] = fmaf(hh, wA[dq].z, acc[nq][2]);
        acc[nq][3] = fmaf(hh, wA[dq].w, acc[nq][3]);
        acc[nq][4] = fmaf(hh, wB[dq].x, acc[nq][4]);
        acc[nq][5] = fmaf(hh, wB[dq].y, acc[nq][5]);
        acc[nq][6] = fmaf(hh, wB[dq].z, acc[nq][6]);
        acc[nq][7] = fmaf(hh, wB[dq].w, acc[nq][7]);
      }
    }
  }
  if (isXl){
    #pragma unroll
    for (int nq=0; nq<8; ++nq){
      int node = n0 + nb + nq;
      if (node < Nn){
        uint4 pk;
        pk.x = (unsigned int)f2bf(acc[nq][0]) | ((unsigned int)f2bf(acc[nq][1])<<16);
        pk.y = (unsigned int)f2bf(acc[nq][2]) | ((unsigned int)f2bf(acc[nq][3])<<16);
        pk.z = (unsigned int)f2bf(acc[nq][4]) | ((unsigned int)f2bf(acc[nq][5])<<16);
        pk.w = (unsigned int)f2bf(acc[nq][6]) | ((unsigned int)f2bf(acc[nq][7])<<16);
        *reinterpret_cast<uint4*>(xlb + (size_t)node*256 + col) = pk;
      }
    }
  } else {
    #pragma unroll
    for (int nq=0; nq<8; ++nq){
      int node = n0 + nb + nq;
      if (node < Nn){
        float4 oA = make_float4(acc[nq][0],acc[nq][1],acc[nq][2],acc[nq][3]);
        float4 oB = make_float4(acc[nq][4],acc[nq][5],acc[nq][6],acc[nq][7]);
        *reinterpret_cast<float4*>(xr + (size_t)node*256 + col)     = oA;
        *reinterpret_cast<float4*>(xr + (size_t)node*256 + col + 4) = oB;
      }
    }
  }
}

// ---------------- edge phase: GATv2 attention aggregation (xl in bf16) ----------------

__global__ __launch_bounds__(256) void k_edge(
    const unsigned short* __restrict__ xlb, const float* __restrict__ xr,
    const int* __restrict__ indptr, const float4* __restrict__ meta,
    const float* __restrict__ We, const float* __restrict__ att,
    float* __restrict__ gat_out)
{
  int lane = threadIdx.x & 63;
  int n = __builtin_amdgcn_readfirstlane(blockIdx.x*4 + (threadIdx.x>>6));
  int coff = (lane>>4)*64 + (lane & 15)*4;

  const float4 xr4 = *reinterpret_cast<const float4*>(xr + (size_t)n*256 + coff);
  const float4 we0 = *reinterpret_cast<const float4*>(We + 0*256 + coff);
  const float4 we1 = *reinterpret_cast<const float4*>(We + 1*256 + coff);
  const float4 we2 = *reinterpret_cast<const float4*>(We + 2*256 + coff);
  const float4 aw  = *reinterpret_cast<const float4*>(att + coff);

  int p0 = __builtin_amdgcn_readfirstlane(indptr[n]);
  int p1 = __builtin_amdgcn_readfirstlane(indptr[n+1]);
  int cnt = p1 - p0;                       // >= 1 (self loop)
  const float4* __restrict__ mp = meta + p0;
  int lane7 = lane & 7;
  int ntiles = (cnt + 7) >> 3;

  float den = 0.f, a0c=0.f, a1c=0.f, a2c=0.f, a3c=0.f;

  auto ldm = [&](int t) -> float4 {
    int idx = t*8 + lane7;
    idx = idx < cnt-1 ? idx : cnt-1;
    return mp[idx];
  };
  auto issueXv = [&](const float4& mb, ushort4 (&xv)[8]){
    #pragma unroll
    for (int i=0;i<8;++i){
      int s = __float_as_int(__shfl(mb.x, i));
      xv[i] = *reinterpret_cast<const ushort4*>(xlb + (size_t)s*256 + coff);
    }
  };
  auto compute = [&](const float4& mb, const ushort4 (&xv)[8], int t){
    #pragma unroll
    for (int i=0;i<8;++i){
      float x0 = bf2f(xv[i].x), x1 = bf2f(xv[i].y);
      float x2 = bf2f(xv[i].z), x3 = bf2f(xv[i].w);
      float a0 = __shfl(mb.y, i), a1 = __shfl(mb.z, i), a2 = __shfl(mb.w, i);
      float t0 = fmaf(a0, we0.x, xr4.x); t0 = fmaf(a1, we1.x, t0); t0 = fmaf(a2, we2.x, t0);
      float t1 = fmaf(a0, we0.y, xr4.y); t1 = fmaf(a1, we1.y, t1); t1 = fmaf(a2, we2.y, t1);
      float t2 = fmaf(a0, we0.z, xr4.z); t2 = fmaf(a1, we1.z, t2); t2 = fmaf(a2, we2.z, t2);
      float t3 = fmaf(a0, we0.w, xr4.w); t3 = fmaf(a1, we1.w, t3); t3 = fmaf(a2, we2.w, t3);
      float u0 = lrelu(x0 + t0), u1 = lrelu(x1 + t1);
      float u2 = lrelu(x2 + t2), u3 = lrelu(x3 + t3);
      float part = fmaf(u0, aw.x, fmaf(u1, aw.y, fmaf(u2, aw.z, u3*aw.w)));
      part += __shfl_xor(part,1); part += __shfl_xor(part,2);
      part += __shfl_xor(part,4); part += __shfl_xor(part,8);
      float w = (t*8 + i < cnt) ? __expf(part) : 0.f;   // logits tiny: no max needed
      den += w;
      a0c = fmaf(w, x0, a0c);
      a1c = fmaf(w, x1, a1c);
      a2c = fmaf(w, x2, a2c);
      a3c = fmaf(w, x3, a3c);
    }
  };

  ushort4 xvA[8], xvB[8];
  float4 mCur = ldm(0);
  float4 mNxt = (ntiles > 1) ? ldm(1) : mCur;
  float4 mN2  = mCur;
  issueXv(mCur, xvA);

  int t = 0;
  while (true){
    if (t+2 < ntiles) mN2 = ldm(t+2);
    if (t+1 < ntiles) issueXv(mNxt, xvB);
    compute(mCur, xvA, t);
    if (t+1 >= ntiles) break;
    if (t+3 < ntiles) mCur = ldm(t+3);
    if (t+2 < ntiles) issueXv(mN2, xvA);
    compute(mNxt, xvB, t+1);
    if (t+2 >= ntiles) break;
    float4 tm = mCur; mCur = mN2; mNxt = tm;
    t += 2;
  }

  float inv = 1.f/(den*(float)Hh);
  float s0=a0c*inv, s1=a1c*inv, s2=a2c*inv, s3=a3c*inv;
  s0 += __shfl_xor(s0,16); s0 += __shfl_xor(s0,32);
  s1 += __shfl_xor(s1,16); s1 += __shfl_xor(s1,32);
  s2 += __shfl_xor(s2,16); s2 += __shfl_xor(s2,32);
  s3 += __shfl_xor(s3,16); s3 += __shfl_xor(s3,32);
  int srcl = lane >> 2;
  float w0 = __shfl(s0, srcl), w1 = __shfl(s1, srcl);
  float w2 = __shfl(s2, srcl), w3 = __shfl(s3, srcl);
  int kk = lane & 3;
  float gat = (kk==0)? w0 : (kk==1)? w1 : (kk==2)? w2 : w3;
  gat_out[(size_t)n*64 + lane] = gat;
}

// ---------------- node phase v5: lane = node, LDS-staged weights ----------------

__global__ __launch_bounds__(256) void k_node(
    float* __restrict__ h, const float* __restrict__ gat,
    const float* __restrict__ gatb,
    const float* __restrict__ ln1w, const float* __restrict__ ln1b,
    const float* __restrict__ fW1T, const float* __restrict__ fb1,
    const float* __restrict__ fW2,  const float* __restrict__ fb2,
    const float* __restrict__ ln2w, const float* __restrict__ ln2b,
    const float* __restrict__ gW1T, const float* __restrict__ gb1,
    const float* __restrict__ gW2,  const float* __restrict__ gb2,
    const int* __restrict__ batch, float* __restrict__ g_sum, float* __restrict__ g_max)
{
  __shared__ float4 sW4[4096];   // 64KB: {W1T|W2} -> {gW1T|gW2} -> 4x [64][64] transpose tiles
  __shared__ int    sB[256];
  float* sW = reinterpret_cast<float*>(sW4);
  int tid  = threadIdx.x;
  int lane = tid & 63;
  int wv   = tid >> 6;
  int n = blockIdx.x*256 + wv*64 + lane;
  bool valid = n < Nn;
  sB[tid] = valid ? batch[n] : -1;

  // cooperative stage of FFN weights (W1T 8192f, W2 8192f)
  {
    const float4* s1 = reinterpret_cast<const float4*>(fW1T);
    const float4* s2 = reinterpret_cast<const float4*>(fW2);
    for (int k=tid; k<2048; k+=256) sW4[k] = s1[k];
    for (int k=tid; k<2048; k+=256) sW4[2048+k] = s2[k];
  }

  // x = h[n] + gat[n] + gatb  (independent of staging; overlaps it)
  float x[64];
  if (valid){
    #pragma unroll
    for (int q=0; q<16; ++q){
      float4 a = *reinterpret_cast<const float4*>(h   + (size_t)n*64 + q*4);
      float4 b = *reinterpret_cast<const float4*>(gat + (size_t)n*64 + q*4);
      float4 g = *reinterpret_cast<const float4*>(gatb + q*4);
      x[q*4+0] = a.x + b.x + g.x;
      x[q*4+1] = a.y + b.y + g.y;
      x[q*4+2] = a.z + b.z + g.z;
      x[q*4+3] = a.w + b.w + g.w;
    }
  } else {
    #pragma unroll
    for (int d=0; d<64; ++d) x[d] = 0.f;
  }

  // LN1 (in-lane)
  {
    float s0=0,s1=0,s2=0,s3=0;
    #pragma unroll
    for (int d=0; d<64; d+=4){ s0+=x[d]; s1+=x[d+1]; s2+=x[d+2]; s3+=x[d+3]; }
    float mean = ((s0+s1)+(s2+s3)) * (1.f/64.f);
    float v0=0,v1=0,v2=0,v3=0;
    #pragma unroll
    for (int d=0; d<64; d+=4){
      float a=x[d]-mean, b=x[d+1]-mean, c=x[d+2]-mean, e=x[d+3]-mean;
      v0=fmaf(a,a,v0); v1=fmaf(b,b,v1); v2=fmaf(c,c,v2); v3=fmaf(e,e,v3);
    }
    float rstd = rsqrtf(((v0+v1)+(v2+v3))*(1.f/64.f) + EPSL);
    #pragma unroll
    for (int d=0; d<64; ++d) x[d] = (x[d]-mean)*rstd*ln1w[d] + ln1b[d];
  }
  __syncthreads();

  // FFN: o[j] = fb2[j] + sum_c lrelu(x.W1T[c] + fb1[c]) * W2[c][j]
  float o[64];
  #pragma unroll
  for (int j=0; j<64; ++j) o[j] = fb2[j];
  #pragma unroll 2
  for (int c=0; c<128; ++c){
    const float* w1 = sW + c*64;
    float a0=0,a1=0,a2=0,a3=0;
    #pragma unroll
    for (int d=0; d<64; d+=4){
      float4 wv4 = *reinterpret_cast<const float4*>(&w1[d]);
      a0 = fmaf(x[d],   wv4.x, a0);
      a1 = fmaf(x[d+1], wv4.y, a1);
      a2 = fmaf(x[d+2], wv4.z, a2);
      a3 = fmaf(x[d+3], wv4.w, a3);
    }
    float hc = lrelu((a0+a1)+(a2+a3) + fb1[c]);
    const float* w2 = sW + 8192 + c*64;
    #pragma unroll
    for (int j=0; j<64; j+=4){
      float4 wv4 = *reinterpret_cast<const float4*>(&w2[j]);
      o[j]   = fmaf(hc, wv4.x, o[j]);
      o[j+1] = fmaf(hc, wv4.y, o[j+1]);
      o[j+2] = fmaf(hc, wv4.z, o[j+2]);
      o[j+3] = fmaf(hc, wv4.w, o[j+3]);
    }
  }
  __syncthreads();

  // restage latent weights (gW1T 4096f, gW2 4096f); LN2 overlaps the stores
  {
    const float4* s1 = reinterpret_cast<const float4*>(gW1T);
    const float4* s2 = reinterpret_cast<const float4*>(gW2);
    for (int k=tid; k<1024; k+=256) sW4[k] = s1[k];
    for (int k=tid; k<1024; k+=256) sW4[1024+k] = s2[k];
  }
  // residual + LN2 -> hn (in x); store h
  {
    #pragma unroll
    for (int d=0; d<64; ++d) x[d] += o[d];
    float s0=0,s1=0,s2=0,s3=0;
    #pragma unroll
    for (int d=0; d<64; d+=4){ s0+=x[d]; s1+=x[d+1]; s2+=x[d+2]; s3+=x[d+3]; }
    float mean = ((s0+s1)+(s2+s3)) * (1.f/64.f);
    float v0=0,v1=0,v2=0,v3=0;
    #pragma unroll
    for (int d=0; d<64; d+=4){
      float a=x[d]-mean, b=x[d+1]-mean, c=x[d+2]-mean, e=x[d+3]-mean;
      v0=fmaf(a,a,v0); v1=fmaf(b,b,v1); v2=fmaf(c,c,v2); v3=fmaf(e,e,v3);
    }
    float rstd = rsqrtf(((v0+v1)+(v2+v3))*(1.f/64.f) + EPSL);
    #pragma unroll
    for (int d=0; d<64; ++d) x[d] = (x[d]-mean)*rstd*ln2w[d] + ln2b[d];
    if (valid){
      #pragma unroll
      for (int q=0; q<16; ++q){
        *reinterpret_cast<float4*>(h + (size_t)n*64 + q*4) =
            make_float4(x[q*4], x[q*4+1], x[q*4+2], x[q*4+3]);
      }
    }
  }
  __syncthreads();

  // latent: lat[j] = gb2[j] + sum_c lrelu(x.gW1T[c] + gb1[c]) * gW2[c][j]
  #pragma unroll
  for (int j=0; j<64; ++j) o[j] = gb2[j];
  #pragma unroll 2
  for (int c=0; c<64; ++c){
    const float* w1 = sW + c*64;
    float a0=0,a1=0,a2=0,a3=0;
    #pragma unroll
    for (int d=0; d<64; d+=4){
      float4 wv4 = *reinterpret_cast<const float4*>(&w1[d]);
      a0 = fmaf(x[d],   wv4.x, a0);
      a1 = fmaf(x[d+1], wv4.y, a1);
      a2 = fmaf(x[d+2], wv4.z, a2);
      a3 = fmaf(x[d+3], wv4.w, a3);
    }
    float uc = lrelu((a0+a1)+(a2+a3) + gb1[c]);
    const float* w2 = sW + 4096 + c*64;
    #pragma unroll
    for (int j=0; j<64; j+=4){
      float4 wv4 = *reinterpret_cast<const float4*>(&w2[j]);
      o[j]   = fmaf(uc, wv4.x, o[j]);
      o[j+1] = fmaf(uc, wv4.y, o[j+1]);
      o[j+2] = fmaf(uc, wv4.z, o[j+2]);
      o[j+3] = fmaf(uc, wv4.w, o[j+3]);
    }
  }
  __syncthreads();   // all waves done reading latent weights; buffer reused below

  // rotation-swizzled transpose tile per wave ([64][64], col=(lane+j)&63 -> <=2-way banks)
  float* sT = sW + wv*4096;
  #pragma unroll
  for (int j=0; j<64; ++j) sT[j*64 + ((lane+j)&63)] = o[j];
  // sorted-run group atomics: lane = dim, iterate this wave's 64 nodes
  {
    int cur = -1; float acc = 0.f, mx = -3.4e38f;
    for (int nn=0; nn<64; ++nn){
      int gv = sB[wv*64 + nn];
      float v = sT[lane*64 + ((nn+lane)&63)];
      if (gv != cur){
        if (cur >= 0){
          atomicAdd(g_sum + cur*64 + lane, acc);
          atomicMaxF(g_max + cur*64 + lane, mx);
        }
        cur = gv; acc = 0.f; mx = -3.4e38f;
      }
      if (gv >= 0){ acc += v; mx = fmaxf(mx, v); }
    }
    if (cur >= 0){
      atomicAdd(g_sum + cur*64 + lane, acc);
      atomicMaxF(g_max + cur*64 + lane, mx);
    }
  }
}

// ---------------- gate (one block), also resets accumulators ----------------

__global__ __launch_bounds__(1024) void k_gate(
    float* __restrict__ g_sum, float* __restrict__ g_max, const int* __restrict__ grp_cnt,
    const float* __restrict__ gW, const float* __restrict__ gb, float* __restrict__ gate)
{
  __shared__ float sme[Gg*64];
  __shared__ float smx[Gg*64];
  int tid = threadIdx.x;
  int g = tid >> 6, d = tid & 63;
  float cnt = fmaxf((float)grp_cnt[g], 1.f);
  sme[tid] = g_sum[tid] / cnt;
  smx[tid] = g_max[tid];
  __syncthreads();
  float a = gb[d];
  #pragma unroll
  for (int j=0;j<64;++j){
    a = fmaf(sme[g*64+j], gW[j*64+d],      a);
    a = fmaf(smx[g*64+j], gW[(64+j)*64+d], a);
  }
  gate[tid] = 1.f/(1.f + __expf(-a));
  g_sum[tid] = 0.f;
  g_max[tid] = -3.4e38f;
}

// ---------------- decoder (applies final gate) ----------------

__global__ __launch_bounds__(256) void k_dec(
    const float* __restrict__ h, const float* __restrict__ gate, const int* __restrict__ batch,
    const float* __restrict__ W1, const float* __restrict__ b1,
    const float* __restrict__ W2, const float* __restrict__ b2,
    float* __restrict__ out)
{
  int lane = threadIdx.x & 63;
  int n = __builtin_amdgcn_readfirstlane(blockIdx.x*4 + (threadIdx.x>>6));
  float hv = h[(size_t)n*64 + lane] * gate[batch[n]*64 + lane];
  float hid = b1[lane];
  #pragma unroll
  for (int d2=0; d2<64; ++d2) hid = fmaf(__shfl(hv,d2), W1[d2*64+lane], hid);
  hid = lrelu(hid);
  float r0 = wsum64(hid * W2[lane*2+0]);
  float r1 = wsum64(hid * W2[lane*2+1]);
  if (lane == 0){
    out[(size_t)n*2]   = r0 + b2[0];
    out[(size_t)n*2+1] = r1 + b2[1];
  }
}

// ---------------- launch ----------------

extern "C" void kernel_launch(void* const* d_in, const int* in_sizes, int n_in,
                              void* d_out, int out_size, void* d_ws, size_t ws_size,
                              hipStream_t stream) {
  const float* x    = (const float*)d_in[0];
  const float* ea   = (const float*)d_in[1];
  const int*   ei   = (const int*)  d_in[2];
  const int*   bat  = (const int*)  d_in[3];
  const float* encW = (const float*)d_in[4];
  const float* encb = (const float*)d_in[5];
  const float* Wl   = (const float*)d_in[6];
  const float* bl   = (const float*)d_in[7];
  const float* Wr   = (const float*)d_in[8];
  const float* br   = (const float*)d_in[9];
  const float* We   = (const float*)d_in[10];
  const float* attw = (const float*)d_in[11];
  const float* gatb = (const float*)d_in[12];
  const float* ln1w = (const float*)d_in[13];
  const float* ln1b = (const float*)d_in[14];
  const float* ln2w = (const float*)d_in[15];
  const float* ln2b = (const float*)d_in[16];
  const float* fW1  = (const float*)d_in[17];
  const float* fb1  = (const float*)d_in[18];
  const float* fW2  = (const float*)d_in[19];
  const float* fb2  = (const float*)d_in[20];
  const float* gW1  = (const float*)d_in[21];
  const float* gb1  = (const float*)d_in[22];
  const float* gW2  = (const float*)d_in[23];
  const float* gb2  = (const float*)d_in[24];
  const float* g2nW = (const float*)d_in[25];
  const float* g2nb = (const float*)d_in[26];
  const float* dW1  = (const float*)d_in[27];
  const float* db1  = (const float*)d_in[28];
  const float* dW2  = (const float*)d_in[29];
  const float* db2  = (const float*)d_in[30];
  float* out = (float*)d_out;

  char* w = (char*)d_ws;
  float*  h    = (float*)w;  w += (size_t)Nn*64*4;
  unsigned short* xlb = (unsigned short*)w; w += (size_t)Nn*256*2;
  float*  xr   = (float*)w;  w += (size_t)Nn*256*4;
  float4* meta = (float4*)w; w += (size_t)Et*16;
  float*  gatv = (float*)w;  w += (size_t)Nn*64*4;
  float* fW1T = (float*)w; w += (size_t)Ll*128*64*4;
  float* gW1T = (float*)w; w += (size_t)Ll*64*64*4;
  float* gate = (float*)w; w += 1024*4;
  float* gsum = (float*)w; w += 1024*4;
  float* gmax = (float*)w; w += 1024*4;
  float* easum  = (float*)w; w += 16;
  float* eamean = (float*)w; w += 16;
  int* deg    = (int*)w; w += (size_t)Nn*4;
  int* indptr = (int*)w; w += (size_t)(Nn+1)*4;
  int* fill   = (int*)w; w += (size_t)Nn*4;
  int* gcnt   = (int*)w; w += 64;

  const int* ei_src = ei;
  const int* ei_dst = ei + Ee;

  k_init   <<<(Nn+255)/256, 256, 0, stream>>>(deg, gsum, gmax, gcnt, easum);
  k_eamean <<<256, 256, 0, stream>>>(ea, easum);
  k_deg    <<<(Et+255)/256, 256, 0, stream>>>(ei_dst, deg);
  k_bcnt   <<<(Nn+255)/256, 256, 0, stream>>>(bat, gcnt);
  k_scan   <<<1, 1024, 0, stream>>>(deg, indptr, fill, easum, eamean);
  k_scatter<<<(Et+255)/256, 256, 0, stream>>>(ei_src, ei_dst, ea, eamean, fill, meta);
  k_tw     <<<(Ll*64*128+255)/256, 256, 0, stream>>>(fW1, gW1, fW1T, gW1T);
  k_enc    <<<(Nn*64+255)/256, 256, 0, stream>>>(x, encW, encb, h);

  for (int l=0; l<Ll; ++l){
    k_xlxr<<<(Nn+31)/32, 256, 0, stream>>>(h, l ? gate : nullptr, bat,
        Wl + (size_t)l*64*256, bl + (size_t)l*256,
        Wr + (size_t)l*64*256, br + (size_t)l*256, xlb, xr);
    k_edge<<<Nn/4, 256, 0, stream>>>(xlb, xr, indptr, meta,
        We + (size_t)l*3*256, attw + (size_t)l*Hh*64, gatv);
    k_node<<<(Nn+255)/256, 256, 0, stream>>>(h, gatv,
        gatb + (size_t)l*64,
        ln1w + (size_t)l*64, ln1b + (size_t)l*64,
        fW1T + (size_t)l*128*64, fb1 + (size_t)l*128,
        fW2 + (size_t)l*128*64, fb2 + (size_t)l*64,
        ln2w + (size_t)l*64, ln2b + (size_t)l*64,
        gW1T + (size_t)l*64*64, gb1 + (size_t)l*64,
        gW2 + (size_t)l*64*64, gb2 + (size_t)l*64,
        bat, gsum, gmax);
    k_gate<<<1, 1024, 0, stream>>>(gsum, gmax, gcnt,
        g2nW + (size_t)l*128*64, g2nb + (size_t)l*64, gate);
  }

  k_dec<<<Nn/4, 256, 0, stream>>>(h, gate, bat, dW1, db1, dW2, db2, out);
}